// Round 27
// baseline (209.514 us; speedup 1.0000x reference)
//
#include <hip/hip_runtime.h>
#include <math.h>

#define NPTS 4096

typedef __attribute__((ext_vector_type(8))) short bf16x8;
typedef __attribute__((ext_vector_type(16))) float f32x16;
typedef long fp8x8;   // 8 fp8 bytes = one 32x32x16_fp8 A/B fragment per lane

// liveness pin: forbid rematerialization / load sinking (round-5 lesson)
#define KEEP(x) asm volatile("" : "+v"(x))

__device__ __forceinline__ f32x16 zero16() {
  f32x16 z;
#pragma unroll
  for (int i = 0; i < 16; ++i) z[i] = 0.f;
  return z;
}

// monotonic sortable key (ascending with float value) with 12-bit m index
__device__ __forceinline__ unsigned packkey(float x, int m) {
  unsigned u = __float_as_uint(x);
  unsigned key = u ^ ((unsigned)((int)u >> 31) | 0x80000000u);
  return (key & 0xFFFFF000u) | (unsigned)m;
}

// cascade insert into sorted-descending 7-array: 7 umax + 7 umin, no branches
__device__ __forceinline__ void cas7(unsigned v, unsigned* s) {
#pragma unroll
  for (int t = 0; t < 7; ++t) {
    const unsigned hi = s[t] >= v ? s[t] : v;
    const unsigned lo = s[t] >= v ? v : s[t];
    s[t] = hi;
    v = lo;
  }
}

#define KSENT 0u

__device__ __forceinline__ unsigned bf16pack(float a, float b) {
  unsigned ua = __float_as_uint(a); ua = (ua + 0x7FFFu + ((ua >> 16) & 1u)) >> 16;
  unsigned ub = __float_as_uint(b); ub = (ub + 0x7FFFu + ((ub >> 16) & 1u)) >> 16;
  return ua | (ub << 16);
}

// ---------------------------------------------------------------------------
// K1: fused normalize: features -> fp8 e4m3 x8 fragment-major Fsw8, codes ->
// bf16 fragment-major Csw (pad 90->96) + fp32 inverse code norms.
// ---------------------------------------------------------------------------
__global__ __launch_bounds__(64) void norm_all(const float* __restrict__ feats,
                                               const float* __restrict__ codes,
                                               unsigned char* __restrict__ Fsw8,
                                               unsigned short* __restrict__ Csw,
                                               float* __restrict__ invc) {
  const int row = blockIdx.x;            // 0 .. 8191
  const int lane = threadIdx.x;
  const int b = row >> 12, mt = (row >> 5) & 127, rl = row & 31;

  const float* f = feats + (size_t)row * 384;
  float v[8];
  float ss = 0.f;
  if (lane < 48) {
    float4 p0 = *(const float4*)(f + lane * 8);
    float4 p1 = *(const float4*)(f + lane * 8 + 4);
    v[0] = p0.x; v[1] = p0.y; v[2] = p0.z; v[3] = p0.w;
    v[4] = p1.x; v[5] = p1.y; v[6] = p1.z; v[7] = p1.w;
#pragma unroll
    for (int e = 0; e < 8; ++e) ss = fmaf(v[e], v[e], ss);
  }
#pragma unroll
  for (int m = 1; m <= 32; m <<= 1) ss += __shfl_xor(ss, m, 64);
  const float s8 = rsqrtf(ss + 1e-8f) * 8.0f;   // x8: e4m3 sweet spot
  if (lane < 48) {
    int w0 = __builtin_amdgcn_cvt_pk_fp8_f32(v[0] * s8, v[1] * s8, 0, 0);
    w0 = __builtin_amdgcn_cvt_pk_fp8_f32(v[2] * s8, v[3] * s8, w0, 1);
    int w1 = __builtin_amdgcn_cvt_pk_fp8_f32(v[4] * s8, v[5] * s8, 0, 0);
    w1 = __builtin_amdgcn_cvt_pk_fp8_f32(v[6] * s8, v[7] * s8, w1, 1);
    const int kc = lane >> 1, hs = lane & 1;
    uint2 o = make_uint2((unsigned)w0, (unsigned)w1);
    *(uint2*)(Fsw8 + (((size_t)(b * 128 + mt) * 24 + kc) << 9) + (hs * 32 + rl) * 8) = o;
  }

  const float* c = codes + (size_t)row * 90;
  float cv[8];
#pragma unroll
  for (int e = 0; e < 8; ++e) cv[e] = 0.f;
  if (lane < 11) {
    float4 p0 = *(const float4*)(c + lane * 8);
    float4 p1 = *(const float4*)(c + lane * 8 + 4);
    cv[0] = p0.x; cv[1] = p0.y; cv[2] = p0.z; cv[3] = p0.w;
    cv[4] = p1.x; cv[5] = p1.y; cv[6] = p1.z; cv[7] = p1.w;
  } else if (lane == 11) {
    cv[0] = c[88]; cv[1] = c[89];
  }
  float cs = 0.f;
#pragma unroll
  for (int e = 0; e < 8; ++e) cs = fmaf(cv[e], cv[e], cs);
#pragma unroll
  for (int m = 1; m <= 32; m <<= 1) cs += __shfl_xor(cs, m, 64);
  const float cinv = rsqrtf(cs + 1e-8f);
  if (lane < 12) {
    uint4 o;
    o.x = bf16pack(cv[0] * cinv, cv[1] * cinv);
    o.y = bf16pack(cv[2] * cinv, cv[3] * cinv);
    o.z = bf16pack(cv[4] * cinv, cv[5] * cinv);
    o.w = bf16pack(cv[6] * cinv, cv[7] * cinv);
    const int kc = lane >> 1, hs = lane & 1;
    *(uint4*)(Csw + (((size_t)(b * 128 + mt) * 6 + kc) << 9) + (hs * 32 + rl) * 8) = o;
  }
  if (lane == 0) invc[row] = cinv;
}

// ---------------------------------------------------------------------------
// K2: feature similarities via 32x32x16 FP8 MFMA (swapped: D[m][q]) + top-7.
// r22-verified best: TWO q-tiles per block share one A-panel sweep. Grid 256
// = qp(64) x b(2) x mhalf(2), 1024-thr blocks; wave w sweeps 4 tiles.
// ---------------------------------------------------------------------------
__global__ __launch_bounds__(1024) void knn_mfma(const unsigned char* __restrict__ Fsw8,
                                                 unsigned* __restrict__ cand) {
  __shared__ unsigned long long qfrag[2 * 24 * 64];   // 24 KB: 2 q-tiles
  __shared__ unsigned ckey[16][64][7];                // 28 KB
  const int g = blockIdx.x;              // 0..255
  const int b = g & 1;
  const int h = (g >> 1) & 1;            // m-half
  const int qp = g >> 2;                 // q-pair 0..63
  const int q0 = qp * 64;
  const int tid = threadIdx.x;
  const int w = tid >> 6;                // 0..15
  const int lane = tid & 63;
  const int lo = lane & 31, hi4 = (lane >> 5) * 4;
  const unsigned char* Fb = Fsw8 + (size_t)b * 128 * 24 * 512;

  {
    const unsigned long long* src =
        (const unsigned long long*)(Fb + ((size_t)(qp * 2) * 24) * 512);
#pragma unroll
    for (int k = 0; k < 3; ++k) qfrag[tid + k * 1024] = src[tid + k * 1024];
  }
  __syncthreads();

  unsigned s7a[7], s7b[7];
#pragma unroll
  for (int t = 0; t < 7; ++t) { s7a[t] = KSENT; s7b[t] = KSENT; }

  const int t0 = h * 64 + w * 4;         // wave's first tile (4 tiles)
  const unsigned char* ab = Fb + ((size_t)t0 * 24) * 512 + lane * 8;

  fp8x8 a0[12], a1[12], bq[12];
#pragma unroll
  for (int t = 0; t < 12; ++t) a0[t] = *(const fp8x8*)(ab + t * 512);

  for (int mt = 0; mt < 4; ++mt) {
    const unsigned char* art = ab + (size_t)mt * 24 * 512;
#pragma unroll
    for (int t = 0; t < 12; ++t) a1[t] = *(const fp8x8*)(art + (12 + t) * 512);
    f32x16 acc0 = zero16(), acc1 = zero16();
#pragma unroll
    for (int t = 0; t < 12; ++t) bq[t] = (fp8x8)qfrag[t * 64 + lane];
#pragma unroll
    for (int t = 0; t < 12; ++t)
      acc0 = __builtin_amdgcn_mfma_f32_32x32x16_fp8_fp8(a0[t], bq[t], acc0, 0, 0, 0);
#pragma unroll
    for (int t = 0; t < 12; ++t) bq[t] = (fp8x8)qfrag[1536 + t * 64 + lane];
#pragma unroll
    for (int t = 0; t < 12; ++t)
      acc1 = __builtin_amdgcn_mfma_f32_32x32x16_fp8_fp8(a0[t], bq[t], acc1, 0, 0, 0);
#pragma unroll
    for (int t = 0; t < 12; ++t) KEEP(a1[t]);
    if (mt + 1 < 4) {
      const unsigned char* arn = ab + (size_t)(mt + 1) * 24 * 512;
#pragma unroll
      for (int t = 0; t < 12; ++t) a0[t] = *(const fp8x8*)(arn + t * 512);
    }
#pragma unroll
    for (int t = 0; t < 12; ++t) bq[t] = (fp8x8)qfrag[(12 + t) * 64 + lane];
#pragma unroll
    for (int t = 0; t < 12; ++t)
      acc0 = __builtin_amdgcn_mfma_f32_32x32x16_fp8_fp8(a1[t], bq[t], acc0, 0, 0, 0);
#pragma unroll
    for (int t = 0; t < 12; ++t) bq[t] = (fp8x8)qfrag[1536 + (12 + t) * 64 + lane];
#pragma unroll
    for (int t = 0; t < 12; ++t)
      acc1 = __builtin_amdgcn_mfma_f32_32x32x16_fp8_fp8(a1[t], bq[t], acc1, 0, 0, 0);
    const int mb = (t0 + mt) * 32 + hi4;
#pragma unroll
    for (int r = 0; r < 16; ++r) {
      const int m = mb + (r & 3) + 8 * (r >> 2);
      cas7(packkey(acc0[r], m), s7a);
      cas7(packkey(acc1[r], m), s7b);
    }
  }

  // merge lane pairs (lane, lane^32) covering the same q-column
#pragma unroll
  for (int t = 0; t < 7; ++t) {
    const unsigned ova = (unsigned)__shfl_xor((int)s7a[t], 32, 64);
    const unsigned ovb = (unsigned)__shfl_xor((int)s7b[t], 32, 64);
    cas7(ova, s7a);
    cas7(ovb, s7b);
  }
  if (lane < 32) {
#pragma unroll
    for (int t = 0; t < 7; ++t) {
      ckey[w][lo][t] = s7a[t];
      ckey[w][32 + lo][t] = s7b[t];
    }
  }
  __syncthreads();

  // block merge: 64 threads, one q each, scan 16 waves x 7 keys -> cand
  if (tid < 64) {
    unsigned fs[7];
#pragma unroll
    for (int t = 0; t < 7; ++t) fs[t] = KSENT;
    for (int w2 = 0; w2 < 16; ++w2)
#pragma unroll
      for (int t = 0; t < 7; ++t) cas7(ckey[w2][tid][t], fs);
    unsigned* o = cand + ((size_t)((h * 2 + b) * NPTS) + q0 + tid) * 7;
#pragma unroll
    for (int t = 0; t < 7; ++t) o[t] = fs[t];
  }
}

// ---------------------------------------------------------------------------
// K3: code similarities -> LSE (fixed shift 10 = self logit) + depth-Gaussian
// weighted sum, PLUS (round-27) the fused positive-pair gather: each block
// additionally handles 32 gather rows (wave w does rows g*32 + w*2 + {0,1}),
// removing the separate 8192-tiny-block gather kernel (~9 us + launch gap).
// Gather body is r22/r26-verified, appended unchanged.
// ---------------------------------------------------------------------------
__global__ __launch_bounds__(1024) void lse_depth(const unsigned short* __restrict__ Csw,
                                                  const float* __restrict__ depth,
                                                  const float* __restrict__ codes,
                                                  const float* __restrict__ invc,
                                                  const unsigned* __restrict__ cand,
                                                  float* __restrict__ lse_out,
                                                  float* __restrict__ dpart,
                                                  float* __restrict__ gpart) {
  __shared__ float lsep[16][32];
  __shared__ float depp[16];
  const int g = blockIdx.x;              // 0..255
  const int b = g & 1;
  const int qt = g >> 1;
  const int q0 = qt * 32;
  const int tid = threadIdx.x;
  const int w = tid >> 6;                // 0..15
  const int lane = tid & 63;
  const int lo = lane & 31, hi4 = (lane >> 5) * 4;
  const unsigned short* Cb = Csw + (size_t)b * 128 * 6 * 512;
  const float* db = depth + b * NPTS;

  bf16x8 bfr[6];
  {
    const unsigned short* qb = Cb + ((size_t)qt * 6) * 512 + lane * 8;
#pragma unroll
    for (int t = 0; t < 6; ++t) bfr[t] = *(const bf16x8*)(qb + t * 512);
#pragma unroll
    for (int t = 0; t < 6; ++t) KEEP(bfr[t]);
  }
  const float dq = db[q0 + lo];
  float slse = 0.f, sdep = 0.f;

  const int t0 = w * 8;                  // 8 tiles per wave
  const unsigned short* ab = Cb + ((size_t)t0 * 6) * 512 + lane * 8;

  bf16x8 a0[6], a1[6];
#pragma unroll
  for (int t = 0; t < 6; ++t) a0[t] = *(const bf16x8*)(ab + t * 512);
#pragma unroll
  for (int t = 0; t < 6; ++t) KEEP(a0[t]);

#define PROC3(A, GT)                                                           \
  {                                                                            \
    f32x16 acc = zero16();                                                     \
    _Pragma("unroll")                                                          \
    for (int t = 0; t < 6; ++t)                                                \
      acc = __builtin_amdgcn_mfma_f32_32x32x16_bf16(A[t], bfr[t], acc, 0, 0, 0); \
    float dvv[16];                                                             \
    _Pragma("unroll")                                                          \
    for (int k = 0; k < 4; ++k) {                                              \
      float4 dv = *(const float4*)(db + (GT) * 32 + hi4 + 8 * k);              \
      dvv[k * 4 + 0] = dv.x; dvv[k * 4 + 1] = dv.y;                            \
      dvv[k * 4 + 2] = dv.z; dvv[k * 4 + 3] = dv.w;                            \
    }                                                                          \
    _Pragma("unroll")                                                          \
    for (int r = 0; r < 16; ++r) {                                             \
      const float s = acc[r];                                                  \
      const float dd = dq - dvv[r];                                            \
      sdep += __expf(-2.f * dd * dd) * (1.f - s);                              \
      slse += __expf(fmaf(s, 10.f, -10.f));                                    \
    }                                                                          \
  }

  for (int mt = 0; mt < 8; mt += 2) {
    {
      const unsigned short* ar = ab + (size_t)(mt + 1) * 6 * 512;
#pragma unroll
      for (int t = 0; t < 6; ++t) a1[t] = *(const bf16x8*)(ar + t * 512);
    }
    PROC3(a0, t0 + mt)
#pragma unroll
    for (int t = 0; t < 6; ++t) KEEP(a1[t]);
    if (mt + 2 < 8) {
      const unsigned short* ar = ab + (size_t)(mt + 2) * 6 * 512;
#pragma unroll
      for (int t = 0; t < 6; ++t) a0[t] = *(const bf16x8*)(ar + t * 512);
    }
    PROC3(a1, t0 + mt + 1)
    if (mt + 2 < 8) {
#pragma unroll
      for (int t = 0; t < 6; ++t) KEEP(a0[t]);
    }
  }
#undef PROC3

  slse += __shfl_xor(slse, 32, 64);
  if (lane < 32) lsep[w][lo] = slse;
#pragma unroll
  for (int m = 1; m <= 32; m <<= 1) sdep += __shfl_xor(sdep, m, 64);
  if (lane == 0) depp[w] = sdep;
  __syncthreads();
  if (tid < 32) {
    float tot = 0.f;
#pragma unroll
    for (int w2 = 0; w2 < 16; ++w2) tot += lsep[w2][tid];
    lse_out[(size_t)(b * NPTS) + q0 + tid] = 10.f + __logf(tot);
  }
  if (tid == 32) {
    float d = 0.f;
#pragma unroll
    for (int w2 = 0; w2 < 16; ++w2) d += depp[w2];
    dpart[g] = d;
  }

  // --------- fused gather: wave w handles rows g*32 + w*2 + {0,1} ----------
#pragma unroll
  for (int rr = 0; rr < 2; ++rr) {
    const int n = g * 32 + w * 2 + rr;   // 0..8191
    const int gb = n >> 12, gq = n & 4095;

    unsigned s[7];
#pragma unroll
    for (int t = 0; t < 7; ++t) s[t] = KSENT;
    const unsigned* c0 = cand + ((size_t)(gb * NPTS) + gq) * 7;
    const unsigned* c1 = cand + ((size_t)((2 + gb) * NPTS) + gq) * 7;
#pragma unroll
    for (int t = 0; t < 7; ++t) cas7(c0[t], s);
#pragma unroll
    for (int t = 0; t < 7; ++t) cas7(c1[t], s);
    // FORCE self (self-sim is always the reference max)
    bool has = false;
#pragma unroll
    for (int t = 0; t < 7; ++t) has = has || ((s[t] & 4095u) == (unsigned)gq);
    if (!has) s[6] = (unsigned)gq;

    const float* cn = codes + (size_t)n * 90;
    float2 a = make_float2(0.f, 0.f);
    if (lane < 45) a = *(const float2*)(cn + lane * 2);
    const float inva = invc[n];
    float ssum = 0.f;
#pragma unroll
    for (int k = 0; k < 7; ++k) {
      const int m = (int)(s[k] & 4095u);
      const float* cm = codes + ((size_t)(gb << 12) + m) * 90;
      float2 bb = make_float2(0.f, 0.f);
      if (lane < 45) bb = *(const float2*)(cm + lane * 2);
      float p = fmaf(a.x, bb.x, a.y * bb.y);
#pragma unroll
      for (int ww = 1; ww <= 32; ww <<= 1) p += __shfl_xor(p, ww, 64);
      ssum += p * inva * invc[(gb << 12) + m];
    }
    if (lane == 0) gpart[n] = ssum;
  }
}

// ---------------------------------------------------------------------------
// K4: finalize -> (l_stego, l_depthg, total).
// ---------------------------------------------------------------------------
__global__ __launch_bounds__(256) void finalize(const float* __restrict__ lse_out,
                                                const float* __restrict__ gpart,
                                                const float* __restrict__ dpart,
                                                float* __restrict__ out) {
  const int tid = threadIdx.x;
  float s1 = 0.f, s2 = 0.f;
  for (int n = tid; n < 2 * NPTS; n += 256) {
    s1 += lse_out[n];
    s2 += gpart[n];
  }
  float s3 = dpart[tid];
  __shared__ float r1[256], r2[256], r3[256];
  r1[tid] = s1; r2[tid] = s2; r3[tid] = s3;
  __syncthreads();
  for (int s = 128; s > 0; s >>= 1) {
    if (tid < s) { r1[tid] += r1[tid + s]; r2[tid] += r2[tid + s]; r3[tid] += r3[tid + s]; }
    __syncthreads();
  }
  if (tid == 0) {
    const float l_st = (7.f * r1[0] - 10.f * r2[0]) / 57344.f;
    const float l_dp = r3[0] / 33554432.f;
    out[0] = l_st;
    out[1] = l_dp;
    out[2] = l_st + 0.3f * l_dp;
  }
}

// ---------------------------------------------------------------------------
// ws layout (peak 5.28 MB <= proven-safe 8.19 MB, no overlays):
//   invc    @ 0        (32768)
//   cand    @ 32768    (458752)   2 half-lists: 4*4096*7*4
//   Fsw8    @ 491520   (3145728)
//   Csw     @ 3637248  (1572864)
//   lse_out @ 5210112  (32768)
//   dpart   @ 5242880  (1024)
//   gpart   @ 5243904  (32768)   -- end 5276672
// ---------------------------------------------------------------------------
extern "C" void kernel_launch(void* const* d_in, const int* in_sizes, int n_in,
                              void* d_out, int out_size, void* d_ws, size_t ws_size,
                              hipStream_t stream) {
  (void)in_sizes; (void)n_in; (void)out_size; (void)ws_size;
  const float* codes = (const float*)d_in[0];   // (B,N,90)
  const float* feats = (const float*)d_in[1];   // (B,N,384)
  const float* depth = (const float*)d_in[2];   // (B,N)
  float* out = (float*)d_out;

  char* ws = (char*)d_ws;
  float*    invc      = (float*)ws;
  unsigned* cand      = (unsigned*)(ws + 32768);
  unsigned char*  Fsw8 = (unsigned char*)(ws + 491520);
  unsigned short* Csw  = (unsigned short*)(ws + 3637248);
  float*    lse_out   = (float*)(ws + 5210112);
  float*    dpart     = (float*)(ws + 5242880);
  float*    gpart     = (float*)(ws + 5243904);

  norm_all<<<2 * NPTS, 64, 0, stream>>>(feats, codes, Fsw8, Csw, invc);
  knn_mfma<<<256, 1024, 0, stream>>>(Fsw8, cand);
  lse_depth<<<256, 1024, 0, stream>>>(Csw, depth, codes, invc, cand,
                                      lse_out, dpart, gpart);
  finalize<<<1, 256, 0, stream>>>(lse_out, gpart, dpart, out);
}

// Round 28
// 84.547 us; speedup vs baseline: 2.4781x; 2.4781x over previous
//
#include <hip/hip_runtime.h>
#include <math.h>

#define NPTS 4096

typedef __attribute__((ext_vector_type(8))) short bf16x8;
typedef __attribute__((ext_vector_type(16))) float f32x16;
typedef long fp8x8;   // 8 fp8 bytes = one 32x32x16_fp8 A/B fragment per lane

// liveness pin: forbid rematerialization / load sinking (round-5 lesson)
#define KEEP(x) asm volatile("" : "+v"(x))

__device__ __forceinline__ f32x16 zero16() {
  f32x16 z;
#pragma unroll
  for (int i = 0; i < 16; ++i) z[i] = 0.f;
  return z;
}

// monotonic sortable key (ascending with float value) with 12-bit m index
__device__ __forceinline__ unsigned packkey(float x, int m) {
  unsigned u = __float_as_uint(x);
  unsigned key = u ^ ((unsigned)((int)u >> 31) | 0x80000000u);
  return (key & 0xFFFFF000u) | (unsigned)m;
}

// cascade insert into sorted-descending 7-array: 7 umax + 7 umin, no branches
__device__ __forceinline__ void cas7(unsigned v, unsigned* s) {
#pragma unroll
  for (int t = 0; t < 7; ++t) {
    const unsigned hi = s[t] >= v ? s[t] : v;
    const unsigned lo = s[t] >= v ? v : s[t];
    s[t] = hi;
    v = lo;
  }
}

#define KSENT 0u

__device__ __forceinline__ unsigned bf16pack(float a, float b) {
  unsigned ua = __float_as_uint(a); ua = (ua + 0x7FFFu + ((ua >> 16) & 1u)) >> 16;
  unsigned ub = __float_as_uint(b); ub = (ub + 0x7FFFu + ((ub >> 16) & 1u)) >> 16;
  return ua | (ub << 16);
}

// ---------------------------------------------------------------------------
// K1: fused normalize: features -> fp8 e4m3 x8 fragment-major Fsw8, codes ->
// bf16 fragment-major Csw (pad 90->96) + fp32 inverse code norms.
// ---------------------------------------------------------------------------
__global__ __launch_bounds__(64) void norm_all(const float* __restrict__ feats,
                                               const float* __restrict__ codes,
                                               unsigned char* __restrict__ Fsw8,
                                               unsigned short* __restrict__ Csw,
                                               float* __restrict__ invc) {
  const int row = blockIdx.x;            // 0 .. 8191
  const int lane = threadIdx.x;
  const int b = row >> 12, mt = (row >> 5) & 127, rl = row & 31;

  const float* f = feats + (size_t)row * 384;
  float v[8];
  float ss = 0.f;
  if (lane < 48) {
    float4 p0 = *(const float4*)(f + lane * 8);
    float4 p1 = *(const float4*)(f + lane * 8 + 4);
    v[0] = p0.x; v[1] = p0.y; v[2] = p0.z; v[3] = p0.w;
    v[4] = p1.x; v[5] = p1.y; v[6] = p1.z; v[7] = p1.w;
#pragma unroll
    for (int e = 0; e < 8; ++e) ss = fmaf(v[e], v[e], ss);
  }
#pragma unroll
  for (int m = 1; m <= 32; m <<= 1) ss += __shfl_xor(ss, m, 64);
  const float s8 = rsqrtf(ss + 1e-8f) * 8.0f;   // x8: e4m3 sweet spot
  if (lane < 48) {
    int w0 = __builtin_amdgcn_cvt_pk_fp8_f32(v[0] * s8, v[1] * s8, 0, 0);
    w0 = __builtin_amdgcn_cvt_pk_fp8_f32(v[2] * s8, v[3] * s8, w0, 1);
    int w1 = __builtin_amdgcn_cvt_pk_fp8_f32(v[4] * s8, v[5] * s8, 0, 0);
    w1 = __builtin_amdgcn_cvt_pk_fp8_f32(v[6] * s8, v[7] * s8, w1, 1);
    const int kc = lane >> 1, hs = lane & 1;
    uint2 o = make_uint2((unsigned)w0, (unsigned)w1);
    *(uint2*)(Fsw8 + (((size_t)(b * 128 + mt) * 24 + kc) << 9) + (hs * 32 + rl) * 8) = o;
  }

  const float* c = codes + (size_t)row * 90;
  float cv[8];
#pragma unroll
  for (int e = 0; e < 8; ++e) cv[e] = 0.f;
  if (lane < 11) {
    float4 p0 = *(const float4*)(c + lane * 8);
    float4 p1 = *(const float4*)(c + lane * 8 + 4);
    cv[0] = p0.x; cv[1] = p0.y; cv[2] = p0.z; cv[3] = p0.w;
    cv[4] = p1.x; cv[5] = p1.y; cv[6] = p1.z; cv[7] = p1.w;
  } else if (lane == 11) {
    cv[0] = c[88]; cv[1] = c[89];
  }
  float cs = 0.f;
#pragma unroll
  for (int e = 0; e < 8; ++e) cs = fmaf(cv[e], cv[e], cs);
#pragma unroll
  for (int m = 1; m <= 32; m <<= 1) cs += __shfl_xor(cs, m, 64);
  const float cinv = rsqrtf(cs + 1e-8f);
  if (lane < 12) {
    uint4 o;
    o.x = bf16pack(cv[0] * cinv, cv[1] * cinv);
    o.y = bf16pack(cv[2] * cinv, cv[3] * cinv);
    o.z = bf16pack(cv[4] * cinv, cv[5] * cinv);
    o.w = bf16pack(cv[6] * cinv, cv[7] * cinv);
    const int kc = lane >> 1, hs = lane & 1;
    *(uint4*)(Csw + (((size_t)(b * 128 + mt) * 6 + kc) << 9) + (hs * 32 + rl) * 8) = o;
  }
  if (lane == 0) invc[row] = cinv;
}

// ---------------------------------------------------------------------------
// K2: feature similarities via 32x32x16 FP8 MFMA (swapped: D[m][q]) + top-7.
// r22/r26-verified best: TWO q-tiles per block share one A-panel sweep.
// Grid 256 = qp(64) x b(2) x mhalf(2), 1024-thr blocks; wave w sweeps 4 tiles.
// ---------------------------------------------------------------------------
__global__ __launch_bounds__(1024) void knn_mfma(const unsigned char* __restrict__ Fsw8,
                                                 unsigned* __restrict__ cand) {
  __shared__ unsigned long long qfrag[2 * 24 * 64];   // 24 KB: 2 q-tiles
  __shared__ unsigned ckey[16][64][7];                // 28 KB
  const int g = blockIdx.x;              // 0..255
  const int b = g & 1;
  const int h = (g >> 1) & 1;            // m-half
  const int qp = g >> 2;                 // q-pair 0..63
  const int q0 = qp * 64;
  const int tid = threadIdx.x;
  const int w = tid >> 6;                // 0..15
  const int lane = tid & 63;
  const int lo = lane & 31, hi4 = (lane >> 5) * 4;
  const unsigned char* Fb = Fsw8 + (size_t)b * 128 * 24 * 512;

  {
    const unsigned long long* src =
        (const unsigned long long*)(Fb + ((size_t)(qp * 2) * 24) * 512);
#pragma unroll
    for (int k = 0; k < 3; ++k) qfrag[tid + k * 1024] = src[tid + k * 1024];
  }
  __syncthreads();

  unsigned s7a[7], s7b[7];
#pragma unroll
  for (int t = 0; t < 7; ++t) { s7a[t] = KSENT; s7b[t] = KSENT; }

  const int t0 = h * 64 + w * 4;         // wave's first tile (4 tiles)
  const unsigned char* ab = Fb + ((size_t)t0 * 24) * 512 + lane * 8;

  fp8x8 a0[12], a1[12], bq[12];
#pragma unroll
  for (int t = 0; t < 12; ++t) a0[t] = *(const fp8x8*)(ab + t * 512);

  for (int mt = 0; mt < 4; ++mt) {
    const unsigned char* art = ab + (size_t)mt * 24 * 512;
#pragma unroll
    for (int t = 0; t < 12; ++t) a1[t] = *(const fp8x8*)(art + (12 + t) * 512);
    f32x16 acc0 = zero16(), acc1 = zero16();
#pragma unroll
    for (int t = 0; t < 12; ++t) bq[t] = (fp8x8)qfrag[t * 64 + lane];
#pragma unroll
    for (int t = 0; t < 12; ++t)
      acc0 = __builtin_amdgcn_mfma_f32_32x32x16_fp8_fp8(a0[t], bq[t], acc0, 0, 0, 0);
#pragma unroll
    for (int t = 0; t < 12; ++t) bq[t] = (fp8x8)qfrag[1536 + t * 64 + lane];
#pragma unroll
    for (int t = 0; t < 12; ++t)
      acc1 = __builtin_amdgcn_mfma_f32_32x32x16_fp8_fp8(a0[t], bq[t], acc1, 0, 0, 0);
#pragma unroll
    for (int t = 0; t < 12; ++t) KEEP(a1[t]);
    if (mt + 1 < 4) {
      const unsigned char* arn = ab + (size_t)(mt + 1) * 24 * 512;
#pragma unroll
      for (int t = 0; t < 12; ++t) a0[t] = *(const fp8x8*)(arn + t * 512);
    }
#pragma unroll
    for (int t = 0; t < 12; ++t) bq[t] = (fp8x8)qfrag[(12 + t) * 64 + lane];
#pragma unroll
    for (int t = 0; t < 12; ++t)
      acc0 = __builtin_amdgcn_mfma_f32_32x32x16_fp8_fp8(a1[t], bq[t], acc0, 0, 0, 0);
#pragma unroll
    for (int t = 0; t < 12; ++t) bq[t] = (fp8x8)qfrag[1536 + (12 + t) * 64 + lane];
#pragma unroll
    for (int t = 0; t < 12; ++t)
      acc1 = __builtin_amdgcn_mfma_f32_32x32x16_fp8_fp8(a1[t], bq[t], acc1, 0, 0, 0);
    const int mb = (t0 + mt) * 32 + hi4;
#pragma unroll
    for (int r = 0; r < 16; ++r) {
      const int m = mb + (r & 3) + 8 * (r >> 2);
      cas7(packkey(acc0[r], m), s7a);
      cas7(packkey(acc1[r], m), s7b);
    }
  }

  // merge lane pairs (lane, lane^32) covering the same q-column
#pragma unroll
  for (int t = 0; t < 7; ++t) {
    const unsigned ova = (unsigned)__shfl_xor((int)s7a[t], 32, 64);
    const unsigned ovb = (unsigned)__shfl_xor((int)s7b[t], 32, 64);
    cas7(ova, s7a);
    cas7(ovb, s7b);
  }
  if (lane < 32) {
#pragma unroll
    for (int t = 0; t < 7; ++t) {
      ckey[w][lo][t] = s7a[t];
      ckey[w][32 + lo][t] = s7b[t];
    }
  }
  __syncthreads();

  // block merge: 64 threads, one q each, scan 16 waves x 7 keys -> cand
  if (tid < 64) {
    unsigned fs[7];
#pragma unroll
    for (int t = 0; t < 7; ++t) fs[t] = KSENT;
    for (int w2 = 0; w2 < 16; ++w2)
#pragma unroll
      for (int t = 0; t < 7; ++t) cas7(ckey[w2][tid][t], fs);
    unsigned* o = cand + ((size_t)((h * 2 + b) * NPTS) + q0 + tid) * 7;
#pragma unroll
    for (int t = 0; t < 7; ++t) o[t] = fs[t];
  }
}

// ---------------------------------------------------------------------------
// K3: code similarities -> LSE (fixed shift 10 = self logit) + depth-Gaussian
// weighted sum. r22/r26-verified: grid 256 = qt(128) x b(2), 1024-thr /
// 16-wave blocks; wave w sweeps tiles [w*8, w*8+8). Writes final 10+log.
// (r27 lesson: do NOT fuse the gather here -- it spills to scratch.)
// ---------------------------------------------------------------------------
__global__ __launch_bounds__(1024) void lse_depth(const unsigned short* __restrict__ Csw,
                                                  const float* __restrict__ depth,
                                                  float* __restrict__ lse_out,
                                                  float* __restrict__ dpart) {
  __shared__ float lsep[16][32];
  __shared__ float depp[16];
  const int g = blockIdx.x;              // 0..255
  const int b = g & 1;
  const int qt = g >> 1;
  const int q0 = qt * 32;
  const int tid = threadIdx.x;
  const int w = tid >> 6;                // 0..15
  const int lane = tid & 63;
  const int lo = lane & 31, hi4 = (lane >> 5) * 4;
  const unsigned short* Cb = Csw + (size_t)b * 128 * 6 * 512;
  const float* db = depth + b * NPTS;

  bf16x8 bfr[6];
  {
    const unsigned short* qb = Cb + ((size_t)qt * 6) * 512 + lane * 8;
#pragma unroll
    for (int t = 0; t < 6; ++t) bfr[t] = *(const bf16x8*)(qb + t * 512);
#pragma unroll
    for (int t = 0; t < 6; ++t) KEEP(bfr[t]);
  }
  const float dq = db[q0 + lo];
  float slse = 0.f, sdep = 0.f;

  const int t0 = w * 8;                  // 8 tiles per wave
  const unsigned short* ab = Cb + ((size_t)t0 * 6) * 512 + lane * 8;

  bf16x8 a0[6], a1[6];
#pragma unroll
  for (int t = 0; t < 6; ++t) a0[t] = *(const bf16x8*)(ab + t * 512);
#pragma unroll
  for (int t = 0; t < 6; ++t) KEEP(a0[t]);

#define PROC3(A, GT)                                                           \
  {                                                                            \
    f32x16 acc = zero16();                                                     \
    _Pragma("unroll")                                                          \
    for (int t = 0; t < 6; ++t)                                                \
      acc = __builtin_amdgcn_mfma_f32_32x32x16_bf16(A[t], bfr[t], acc, 0, 0, 0); \
    float dvv[16];                                                             \
    _Pragma("unroll")                                                          \
    for (int k = 0; k < 4; ++k) {                                              \
      float4 dv = *(const float4*)(db + (GT) * 32 + hi4 + 8 * k);              \
      dvv[k * 4 + 0] = dv.x; dvv[k * 4 + 1] = dv.y;                            \
      dvv[k * 4 + 2] = dv.z; dvv[k * 4 + 3] = dv.w;                            \
    }                                                                          \
    _Pragma("unroll")                                                          \
    for (int r = 0; r < 16; ++r) {                                             \
      const float s = acc[r];                                                  \
      const float dd = dq - dvv[r];                                            \
      sdep += __expf(-2.f * dd * dd) * (1.f - s);                              \
      slse += __expf(fmaf(s, 10.f, -10.f));                                    \
    }                                                                          \
  }

  for (int mt = 0; mt < 8; mt += 2) {
    {
      const unsigned short* ar = ab + (size_t)(mt + 1) * 6 * 512;
#pragma unroll
      for (int t = 0; t < 6; ++t) a1[t] = *(const bf16x8*)(ar + t * 512);
    }
    PROC3(a0, t0 + mt)
#pragma unroll
    for (int t = 0; t < 6; ++t) KEEP(a1[t]);
    if (mt + 2 < 8) {
      const unsigned short* ar = ab + (size_t)(mt + 2) * 6 * 512;
#pragma unroll
      for (int t = 0; t < 6; ++t) a0[t] = *(const bf16x8*)(ar + t * 512);
    }
    PROC3(a1, t0 + mt + 1)
    if (mt + 2 < 8) {
#pragma unroll
      for (int t = 0; t < 6; ++t) KEEP(a0[t]);
    }
  }
#undef PROC3

  slse += __shfl_xor(slse, 32, 64);
  if (lane < 32) lsep[w][lo] = slse;
#pragma unroll
  for (int m = 1; m <= 32; m <<= 1) sdep += __shfl_xor(sdep, m, 64);
  if (lane == 0) depp[w] = sdep;
  __syncthreads();
  if (tid < 32) {
    float tot = 0.f;
#pragma unroll
    for (int w2 = 0; w2 < 16; ++w2) tot += lsep[w2][tid];
    lse_out[(size_t)(b * NPTS) + q0 + tid] = 10.f + __logf(tot);
  }
  if (tid == 32) {
    float d = 0.f;
#pragma unroll
    for (int w2 = 0; w2 < 16; ++w2) d += depp[w2];
    dpart[g] = d;
  }
}

// ---------------------------------------------------------------------------
// K4: merge the two half-candidate lists, force self, then 7 positive-pair
// code dots in FP32 from raw codes. One wave per row.
// ---------------------------------------------------------------------------
__global__ __launch_bounds__(64) void gather_pos(const float* __restrict__ codes,
                                                 const float* __restrict__ invc,
                                                 const unsigned* __restrict__ cand,
                                                 float* __restrict__ gpart) {
  const int n = blockIdx.x;              // 0..8191 (global row)
  const int b = n >> 12, q = n & 4095;
  const int lane = threadIdx.x;

  unsigned s[7];
#pragma unroll
  for (int t = 0; t < 7; ++t) s[t] = KSENT;
  const unsigned* c0 = cand + ((size_t)(b * NPTS) + q) * 7;
  const unsigned* c1 = cand + ((size_t)((2 + b) * NPTS) + q) * 7;
#pragma unroll
  for (int t = 0; t < 7; ++t) cas7(c0[t], s);
#pragma unroll
  for (int t = 0; t < 7; ++t) cas7(c1[t], s);
  // FORCE self (self-sim is always the reference max)
  bool has = false;
#pragma unroll
  for (int t = 0; t < 7; ++t) has = has || ((s[t] & 4095u) == (unsigned)q);
  if (!has) s[6] = (unsigned)q;

  const float* cn = codes + (size_t)n * 90;
  float2 a = make_float2(0.f, 0.f);
  if (lane < 45) a = *(const float2*)(cn + lane * 2);
  const float inva = invc[n];
  float ssum = 0.f;
#pragma unroll
  for (int k = 0; k < 7; ++k) {
    const int m = (int)(s[k] & 4095u);
    const float* cm = codes + ((size_t)(b << 12) + m) * 90;
    float2 bb = make_float2(0.f, 0.f);
    if (lane < 45) bb = *(const float2*)(cm + lane * 2);
    float p = fmaf(a.x, bb.x, a.y * bb.y);
#pragma unroll
    for (int w = 1; w <= 32; w <<= 1) p += __shfl_xor(p, w, 64);
    ssum += p * inva * invc[(b << 12) + m];
  }
  if (lane == 0) gpart[n] = ssum;
}

// ---------------------------------------------------------------------------
// K5: finalize -> (l_stego, l_depthg, total).
// ---------------------------------------------------------------------------
__global__ __launch_bounds__(256) void finalize(const float* __restrict__ lse_out,
                                                const float* __restrict__ gpart,
                                                const float* __restrict__ dpart,
                                                float* __restrict__ out) {
  const int tid = threadIdx.x;
  float s1 = 0.f, s2 = 0.f;
  for (int n = tid; n < 2 * NPTS; n += 256) {
    s1 += lse_out[n];
    s2 += gpart[n];
  }
  float s3 = dpart[tid];
  __shared__ float r1[256], r2[256], r3[256];
  r1[tid] = s1; r2[tid] = s2; r3[tid] = s3;
  __syncthreads();
  for (int s = 128; s > 0; s >>= 1) {
    if (tid < s) { r1[tid] += r1[tid + s]; r2[tid] += r2[tid + s]; r3[tid] += r3[tid + s]; }
    __syncthreads();
  }
  if (tid == 0) {
    const float l_st = (7.f * r1[0] - 10.f * r2[0]) / 57344.f;
    const float l_dp = r3[0] / 33554432.f;
    out[0] = l_st;
    out[1] = l_dp;
    out[2] = l_st + 0.3f * l_dp;
  }
}

// ---------------------------------------------------------------------------
// ws layout (peak 5.28 MB <= proven-safe 8.19 MB, no overlays):
//   invc    @ 0        (32768)
//   cand    @ 32768    (458752)   2 half-lists: 4*4096*7*4
//   Fsw8    @ 491520   (3145728)
//   Csw     @ 3637248  (1572864)
//   lse_out @ 5210112  (32768)
//   dpart   @ 5242880  (1024)
//   gpart   @ 5243904  (32768)   -- end 5276672
// ---------------------------------------------------------------------------
extern "C" void kernel_launch(void* const* d_in, const int* in_sizes, int n_in,
                              void* d_out, int out_size, void* d_ws, size_t ws_size,
                              hipStream_t stream) {
  (void)in_sizes; (void)n_in; (void)out_size; (void)ws_size;
  const float* codes = (const float*)d_in[0];   // (B,N,90)
  const float* feats = (const float*)d_in[1];   // (B,N,384)
  const float* depth = (const float*)d_in[2];   // (B,N)
  float* out = (float*)d_out;

  char* ws = (char*)d_ws;
  float*    invc      = (float*)ws;
  unsigned* cand      = (unsigned*)(ws + 32768);
  unsigned char*  Fsw8 = (unsigned char*)(ws + 491520);
  unsigned short* Csw  = (unsigned short*)(ws + 3637248);
  float*    lse_out   = (float*)(ws + 5210112);
  float*    dpart     = (float*)(ws + 5242880);
  float*    gpart     = (float*)(ws + 5243904);

  norm_all<<<2 * NPTS, 64, 0, stream>>>(feats, codes, Fsw8, Csw, invc);
  knn_mfma<<<256, 1024, 0, stream>>>(Fsw8, cand);
  lse_depth<<<256, 1024, 0, stream>>>(Csw, depth, lse_out, dpart);
  gather_pos<<<2 * NPTS, 64, 0, stream>>>(codes, invc, cand, gpart);
  finalize<<<1, 256, 0, stream>>>(lse_out, gpart, dpart, out);
}